// Round 14
// baseline (154.151 us; speedup 1.0000x reference)
//
#include <hip/hip_runtime.h>

#define NF    256   // IN_F
#define HD    256   // H*D
#define NH    4
#define DH    64
#define WINS  128   // WIN
#define HALFW 64
#define TOPK  32
#define GROWS 32    // rows per gemm block (4 waves x 8 rows)

// ------------- fused Q/K projection: X[n,256] @ W[256,256] + b -------------
// grid (n/32, 2), 256 threads. Wave = 8 rows; lane owns cols 4l..4l+3.
// TWO stall sources fixed simultaneously (each alone measured flat):
//  - W: 2-stage register pipeline (partial vmcnt waits, R11's -7us)
//  - X: staged once in LDS; per-group b128 same-address broadcast ds_reads
//    are IN-ORDER (partial lgkmcnt), unlike s_loads whose out-of-order
//    return forces a full lgkmcnt(0) drain every k-group (R13's no-op).
__global__ __launch_bounds__(256) void qk_gemm_kernel(
    const float* __restrict__ X,
    const float* __restrict__ Wq, const float* __restrict__ bq,
    const float* __restrict__ Wk, const float* __restrict__ bk,
    float* __restrict__ Qb, float* __restrict__ Kb, int n)
{
    __shared__ float lx[GROWS][NF];            // 32 KB X tile
    const int t    = threadIdx.x;
    const int wave = t >> 6;
    const int lane = t & 63;
    const bool isK = (blockIdx.y != 0);
    const float* W   = isK ? Wk : Wq;
    const float* bia = isK ? bk : bq;
    float*       Out = isK ? Kb : Qb;

    {   // stage X tile: 32 rows x 256 = 2048 float4s, 8/thread, coalesced
        const float4* xsrc = (const float4*)(X + (size_t)blockIdx.x * GROWS * NF);
        float4* xdst = (float4*)&lx[0][0];
#pragma unroll
        for (int j = 0; j < 8; ++j) xdst[j * 256 + t] = xsrc[j * 256 + t];
    }
    __syncthreads();

    const int rw = wave * 8;                   // this wave's rows in the tile

    float4 acc[8];
#pragma unroll
    for (int r = 0; r < 8; ++r) acc[r] = make_float4(0.f, 0.f, 0.f, 0.f);

    float4 wA[8], wB[8];
    const float* Wl = W + 4 * lane;

#pragma unroll
    for (int u = 0; u < 8; ++u)                // prologue: W group 0
        wA[u] = *(const float4*)(Wl + (size_t)u * HD);

    for (int k = 0; k < NF; k += 16) {
        if (k + 8 < NF) {                      // prefetch W group g+1
#pragma unroll
            for (int u = 0; u < 8; ++u)
                wB[u] = *(const float4*)(Wl + (size_t)(k + 8 + u) * HD);
        }
#pragma unroll
        for (int r = 0; r < 8; ++r) {          // X via in-order LDS broadcast
            float4 x0 = *(const float4*)&lx[rw + r][k];
            float4 x1 = *(const float4*)&lx[rw + r][k + 4];
            acc[r].x += x0.x*wA[0].x + x0.y*wA[1].x + x0.z*wA[2].x + x0.w*wA[3].x
                      + x1.x*wA[4].x + x1.y*wA[5].x + x1.z*wA[6].x + x1.w*wA[7].x;
            acc[r].y += x0.x*wA[0].y + x0.y*wA[1].y + x0.z*wA[2].y + x0.w*wA[3].y
                      + x1.x*wA[4].y + x1.y*wA[5].y + x1.z*wA[6].y + x1.w*wA[7].y;
            acc[r].z += x0.x*wA[0].z + x0.y*wA[1].z + x0.z*wA[2].z + x0.w*wA[3].z
                      + x1.x*wA[4].z + x1.y*wA[5].z + x1.z*wA[6].z + x1.w*wA[7].z;
            acc[r].w += x0.x*wA[0].w + x0.y*wA[1].w + x0.z*wA[2].w + x0.w*wA[3].w
                      + x1.x*wA[4].w + x1.y*wA[5].w + x1.z*wA[6].w + x1.w*wA[7].w;
        }
        if (k + 16 < NF) {                     // prefetch W group g+2
#pragma unroll
            for (int u = 0; u < 8; ++u)
                wA[u] = *(const float4*)(Wl + (size_t)(k + 16 + u) * HD);
        }
#pragma unroll
        for (int r = 0; r < 8; ++r) {
            float4 x0 = *(const float4*)&lx[rw + r][k + 8];
            float4 x1 = *(const float4*)&lx[rw + r][k + 12];
            acc[r].x += x0.x*wB[0].x + x0.y*wB[1].x + x0.z*wB[2].x + x0.w*wB[3].x
                      + x1.x*wB[4].x + x1.y*wB[5].x + x1.z*wB[6].x + x1.w*wB[7].x;
            acc[r].y += x0.x*wB[0].y + x0.y*wB[1].y + x0.z*wB[2].y + x0.w*wB[3].y
                      + x1.x*wB[4].y + x1.y*wB[5].y + x1.z*wB[6].y + x1.w*wB[7].y;
            acc[r].z += x0.x*wB[0].z + x0.y*wB[1].z + x0.z*wB[2].z + x0.w*wB[3].z
                      + x1.x*wB[4].z + x1.y*wB[5].z + x1.z*wB[6].z + x1.w*wB[7].z;
            acc[r].w += x0.x*wB[0].w + x0.y*wB[1].w + x0.z*wB[2].w + x0.w*wB[3].w
                      + x1.x*wB[4].w + x1.y*wB[5].w + x1.z*wB[6].w + x1.w*wB[7].w;
        }
    }

    const int r0 = blockIdx.x * GROWS + rw;
    const float4 bv = *(const float4*)(bia + 4 * lane);
#pragma unroll
    for (int r = 0; r < 8; ++r) {
        acc[r].x += bv.x; acc[r].y += bv.y; acc[r].z += bv.z; acc[r].w += bv.w;
        *(float4*)(Out + (size_t)(r0 + r) * HD + 4 * lane) = acc[r];  // coalesced
    }
}

// ---- per-node windowed attention + top-32 + fused full-row write ----
// R10's measured-best kernel + sc stride padded to 136 so the 4 heads'
// sc[h][row] writes (stride-128 = same bank) hit 4 distinct banks.
__global__ __launch_bounds__(256) void attn_topk_kernel(
    const float* __restrict__ Q,
    const float* __restrict__ K,
    const int* __restrict__ nnpg, int n_graphs,
    const int* __restrict__ nrel,
    float* __restrict__ out, int n)
{
    const int i    = blockIdx.x;
    const int t    = threadIdx.x;
    const int wave = t >> 6;
    const int lane = t & 63;

    __shared__ float sc[NH][WINS + 8];  // +8: banks (row+8h)%32 -> conflict-free
    __shared__ float pr[NH][WINS];
    __shared__ float attnv[WINS];
    __shared__ float slotval[WINS];

    // segment bounds: tile(nnpg, R) -> cumsum -> searchsorted(right)
    int R = nrel[0];
    int total = n_graphs * R;
    int seg_start = 0, seg_end = n;
    int cum = 0;
    for (int e = 0; e < total; ++e) {
        int sz = nnpg[e % n_graphs];
        int nc = cum + sz;
        if (i < nc) { seg_start = cum; seg_end = nc; break; }
        cum = nc;
    }
    const int start = max(seg_start, i - HALFW);
    const int end   = min(seg_end,   i + HALFW);
    const int win   = end - start;            // >= 64 (segments >= 128 nodes)

    const float4 q4 = *(const float4*)(Q + (size_t)i * HD + lane * 4);

    // ---- scores: wave w handles rows {w + 4j}; 8-deep independent loads ----
#pragma unroll 8
    for (int j = 0; j < 32; ++j) {
        int row = wave + 4 * j;               // 0..127
        float v = 0.f;
        if (row < win) {
            float4 k4 = *(const float4*)(K + (size_t)(start + row) * HD + lane * 4);
            v = q4.x * k4.x + q4.y * k4.y + q4.z * k4.z + q4.w * k4.w;
        }
        v += __shfl_xor(v, 1);
        v += __shfl_xor(v, 2);
        v += __shfl_xor(v, 4);
        v += __shfl_xor(v, 8);
        if ((lane & 15) == 0)
            sc[lane >> 4][row] = v * 0.25f;   // /sqrt(64)/tau; padded rows -> 0
    }
    __syncthreads();

    // ---- per-head softmax over full 128-slot window: wave w = head w ----
    {
        float v0 = sc[wave][lane], v1 = sc[wave][lane + 64];
        float mx = fmaxf(v0, v1);
#pragma unroll
        for (int off = 32; off > 0; off >>= 1) mx = fmaxf(mx, __shfl_xor(mx, off));
        float e0 = expf(v0 - mx), e1 = expf(v1 - mx);
        float sm = e0 + e1;
#pragma unroll
        for (int off = 32; off > 0; off >>= 1) sm += __shfl_xor(sm, off);
        pr[wave][lane]      = e0 / sm;
        pr[wave][lane + 64] = e1 / sm;
    }
    __syncthreads();

    // ---- mean over heads; invalid slots excluded from top-k ----
    if (t < WINS) {
        float a = 0.25f * (pr[0][t] + pr[1][t] + pr[2][t] + pr[3][t]);
        attnv[t] = (t < win) ? a : -1.0f;
    }
    __syncthreads();

    // ---- stable top-32 rank count (lower index wins ties, like lax.top_k) ----
    if (t < WINS) {
        float v = attnv[t];
        int cnt = 0;
#pragma unroll
        for (int j4 = 0; j4 < WINS / 4; ++j4) {
            float4 a4 = *(const float4*)&attnv[j4 * 4];
            int jb = j4 * 4;
            cnt += (a4.x > v) || (a4.x == v && (jb + 0) < t);
            cnt += (a4.y > v) || (a4.y == v && (jb + 1) < t);
            cnt += (a4.z > v) || (a4.z == v && (jb + 2) < t);
            cnt += (a4.w > v) || (a4.w == v && (jb + 3) < t);
        }
        slotval[t] = (t < win && cnt < TOPK) ? 1.0f : 0.0f;
    }
    __syncthreads();

    // ---- fused full-row write: zeros + window values, float4 stores ----
    float4* orow = (float4*)(out + (size_t)i * n);
    const int n4 = n >> 2;
    for (int c4 = t; c4 < n4; c4 += 256) {
        int c = c4 << 2;
        float4 v4 = make_float4(0.f, 0.f, 0.f, 0.f);
        if (c + 3 >= start && c < end) {
            int o = c - start;
            if (o     >= 0 && o     < WINS) v4.x = slotval[o];
            if (o + 1 >= 0 && o + 1 < WINS) v4.y = slotval[o + 1];
            if (o + 2 >= 0 && o + 2 < WINS) v4.z = slotval[o + 2];
            if (o + 3 >= 0 && o + 3 < WINS) v4.w = slotval[o + 3];
        }
        orow[c4] = v4;
    }
}

extern "C" void kernel_launch(void* const* d_in, const int* in_sizes, int n_in,
                              void* d_out, int out_size, void* d_ws, size_t ws_size,
                              hipStream_t stream)
{
    const float* X  = (const float*)d_in[0];
    const float* Wq = (const float*)d_in[1];
    const float* bq = (const float*)d_in[2];
    const float* Wk = (const float*)d_in[3];
    const float* bk = (const float*)d_in[4];
    const int* nnpg = (const int*)d_in[5];
    const int* nrel = (const int*)d_in[6];

    const int n = in_sizes[0] / NF;
    const int n_graphs = in_sizes[5];

    float* Qb = (float*)d_ws;                 // [n][256]
    float* Kb = Qb + (size_t)n * HD;          // [n][256]
    float* out = (float*)d_out;

    dim3 gg(n / GROWS, 2);
    qk_gemm_kernel<<<gg, 256, 0, stream>>>(X, Wq, bq, Wk, bk, Qb, Kb, n);

    attn_topk_kernel<<<n, 256, 0, stream>>>(Qb, Kb, nnpg, n_graphs, nrel, out, n);
}

// Round 15
// 143.187 us; speedup vs baseline: 1.0766x; 1.0766x over previous
//
#include <hip/hip_runtime.h>

#define NF    256   // IN_F
#define HD    256   // H*D
#define NH    4
#define DH    64
#define WINS  128   // WIN
#define HALFW 64
#define TOPK  32
#define GROWS 32    // rows per gemm block (4 waves x 8 rows)

// ------------- fused Q/K projection: X[n,256] @ W[256,256] + b -------------
// R11's exact kernel (best measured total) + XCD-aware row swizzle:
// block x handles a row chunk inside segment-group x%8, so with round-robin
// block->XCD dispatch (id%8), all rows of node-segment s are computed and
// L2-cached on XCD s — where the attn blocks for segment s (same swizzle)
// will read them. Pure permutation: correctness independent of dispatch.
__global__ __launch_bounds__(256) void qk_gemm_kernel(
    const float* __restrict__ X,
    const float* __restrict__ Wq, const float* __restrict__ bq,
    const float* __restrict__ Wk, const float* __restrict__ bk,
    float* __restrict__ Qb, float* __restrict__ Kb, int n)
{
    const int t    = threadIdx.x;
    const int wave = t >> 6;
    const int lane = t & 63;
    const bool isK = (blockIdx.y != 0);
    const float* W   = isK ? Wk : Wq;
    const float* bia = isK ? bk : bq;
    float*       Out = isK ? Kb : Qb;

    // XCD swizzle: chunk = gx/8 blocks; block x -> chunk x%8, position x/8
    const int gx = gridDim.x;
    int bswz = blockIdx.x;
    if ((gx & 7) == 0) {
        int chunk = gx >> 3;
        bswz = (blockIdx.x & 7) * chunk + (blockIdx.x >> 3);
    }
    const int r0  = bswz * GROWS + wave * 8;
    const int r0s = __builtin_amdgcn_readfirstlane(r0);
    const float* Xs = X + (size_t)r0s * NF;        // scalar base -> s_load

    float4 acc[8];
#pragma unroll
    for (int r = 0; r < 8; ++r) acc[r] = make_float4(0.f, 0.f, 0.f, 0.f);

    float4 wA[8], wB[8];
    const float* Wl = W + 4 * lane;

#pragma unroll
    for (int u = 0; u < 8; ++u)                     // prologue: group 0
        wA[u] = *(const float4*)(Wl + (size_t)u * HD);

    for (int k = 0; k < NF; k += 16) {
        if (k + 8 < NF) {                           // prefetch group g+1
#pragma unroll
            for (int u = 0; u < 8; ++u)
                wB[u] = *(const float4*)(Wl + (size_t)(k + 8 + u) * HD);
        }
#pragma unroll
        for (int u = 0; u < 8; ++u) {
#pragma unroll
            for (int r = 0; r < 8; ++r) {
                float xk = Xs[r * NF + k + u];      // SGPR broadcast
                acc[r].x += xk * wA[u].x;
                acc[r].y += xk * wA[u].y;
                acc[r].z += xk * wA[u].z;
                acc[r].w += xk * wA[u].w;
            }
        }
        if (k + 16 < NF) {                          // prefetch group g+2
#pragma unroll
            for (int u = 0; u < 8; ++u)
                wA[u] = *(const float4*)(Wl + (size_t)(k + 16 + u) * HD);
        }
#pragma unroll
        for (int u = 0; u < 8; ++u) {
#pragma unroll
            for (int r = 0; r < 8; ++r) {
                float xk = Xs[r * NF + k + 8 + u];  // SGPR broadcast
                acc[r].x += xk * wB[u].x;
                acc[r].y += xk * wB[u].y;
                acc[r].z += xk * wB[u].z;
                acc[r].w += xk * wB[u].w;
            }
        }
    }

    const float4 bv = *(const float4*)(bia + 4 * lane);
#pragma unroll
    for (int r = 0; r < 8; ++r) {
        acc[r].x += bv.x; acc[r].y += bv.y; acc[r].z += bv.z; acc[r].w += bv.w;
        *(float4*)(Out + (size_t)(r0 + r) * HD + 4 * lane) = acc[r];  // coalesced
    }
}

// ---- per-node windowed attention + top-32 + fused full-row write ----
// R10's measured-best kernel (53.5us x4 runs) + XCD node swizzle: block b ->
// node (b%8)*(n/8)+b/8, so all nodes of segment s run on XCD s where their
// K window rows (window never crosses the 512-node segment bound) are L2-hot.
__global__ __launch_bounds__(256) void attn_topk_kernel(
    const float* __restrict__ Q,
    const float* __restrict__ K,
    const int* __restrict__ nnpg, int n_graphs,
    const int* __restrict__ nrel,
    float* __restrict__ out, int n)
{
    const int t    = threadIdx.x;
    const int wave = t >> 6;
    const int lane = t & 63;

    int i = blockIdx.x;
    const int nb = gridDim.x;
    if ((nb & 7) == 0) {                      // bijective XCD swizzle
        int chunk = nb >> 3;
        i = (blockIdx.x & 7) * chunk + (blockIdx.x >> 3);
    }

    __shared__ float sc[NH][WINS + 8];  // +8 pad: conflict-free head writes
    __shared__ float pr[NH][WINS];
    __shared__ float attnv[WINS];
    __shared__ float slotval[WINS];

    // segment bounds: tile(nnpg, R) -> cumsum -> searchsorted(right)
    int R = nrel[0];
    int total = n_graphs * R;
    int seg_start = 0, seg_end = n;
    int cum = 0;
    for (int e = 0; e < total; ++e) {
        int sz = nnpg[e % n_graphs];
        int nc = cum + sz;
        if (i < nc) { seg_start = cum; seg_end = nc; break; }
        cum = nc;
    }
    const int start = max(seg_start, i - HALFW);
    const int end   = min(seg_end,   i + HALFW);
    const int win   = end - start;            // >= 64 (segments >= 128 nodes)

    const float4 q4 = *(const float4*)(Q + (size_t)i * HD + lane * 4);

    // ---- scores: wave w handles rows {w + 4j}; 8-deep independent loads ----
#pragma unroll 8
    for (int j = 0; j < 32; ++j) {
        int row = wave + 4 * j;               // 0..127
        float v = 0.f;
        if (row < win) {
            float4 k4 = *(const float4*)(K + (size_t)(start + row) * HD + lane * 4);
            v = q4.x * k4.x + q4.y * k4.y + q4.z * k4.z + q4.w * k4.w;
        }
        v += __shfl_xor(v, 1);
        v += __shfl_xor(v, 2);
        v += __shfl_xor(v, 4);
        v += __shfl_xor(v, 8);
        if ((lane & 15) == 0)
            sc[lane >> 4][row] = v * 0.25f;   // /sqrt(64)/tau; padded rows -> 0
    }
    __syncthreads();

    // ---- per-head softmax over full 128-slot window: wave w = head w ----
    {
        float v0 = sc[wave][lane], v1 = sc[wave][lane + 64];
        float mx = fmaxf(v0, v1);
#pragma unroll
        for (int off = 32; off > 0; off >>= 1) mx = fmaxf(mx, __shfl_xor(mx, off));
        float e0 = expf(v0 - mx), e1 = expf(v1 - mx);
        float sm = e0 + e1;
#pragma unroll
        for (int off = 32; off > 0; off >>= 1) sm += __shfl_xor(sm, off);
        pr[wave][lane]      = e0 / sm;
        pr[wave][lane + 64] = e1 / sm;
    }
    __syncthreads();

    // ---- mean over heads; invalid slots excluded from top-k ----
    if (t < WINS) {
        float a = 0.25f * (pr[0][t] + pr[1][t] + pr[2][t] + pr[3][t]);
        attnv[t] = (t < win) ? a : -1.0f;
    }
    __syncthreads();

    // ---- stable top-32 rank count (lower index wins ties, like lax.top_k) ----
    if (t < WINS) {
        float v = attnv[t];
        int cnt = 0;
#pragma unroll
        for (int j4 = 0; j4 < WINS / 4; ++j4) {
            float4 a4 = *(const float4*)&attnv[j4 * 4];
            int jb = j4 * 4;
            cnt += (a4.x > v) || (a4.x == v && (jb + 0) < t);
            cnt += (a4.y > v) || (a4.y == v && (jb + 1) < t);
            cnt += (a4.z > v) || (a4.z == v && (jb + 2) < t);
            cnt += (a4.w > v) || (a4.w == v && (jb + 3) < t);
        }
        slotval[t] = (t < win && cnt < TOPK) ? 1.0f : 0.0f;
    }
    __syncthreads();

    // ---- fused full-row write: zeros + window values, float4 stores ----
    float4* orow = (float4*)(out + (size_t)i * n);
    const int n4 = n >> 2;
    for (int c4 = t; c4 < n4; c4 += 256) {
        int c = c4 << 2;
        float4 v4 = make_float4(0.f, 0.f, 0.f, 0.f);
        if (c + 3 >= start && c < end) {
            int o = c - start;
            if (o     >= 0 && o     < WINS) v4.x = slotval[o];
            if (o + 1 >= 0 && o + 1 < WINS) v4.y = slotval[o + 1];
            if (o + 2 >= 0 && o + 2 < WINS) v4.z = slotval[o + 2];
            if (o + 3 >= 0 && o + 3 < WINS) v4.w = slotval[o + 3];
        }
        orow[c4] = v4;
    }
}

extern "C" void kernel_launch(void* const* d_in, const int* in_sizes, int n_in,
                              void* d_out, int out_size, void* d_ws, size_t ws_size,
                              hipStream_t stream)
{
    const float* X  = (const float*)d_in[0];
    const float* Wq = (const float*)d_in[1];
    const float* bq = (const float*)d_in[2];
    const float* Wk = (const float*)d_in[3];
    const float* bk = (const float*)d_in[4];
    const int* nnpg = (const int*)d_in[5];
    const int* nrel = (const int*)d_in[6];

    const int n = in_sizes[0] / NF;
    const int n_graphs = in_sizes[5];

    float* Qb = (float*)d_ws;                 // [n][256]
    float* Kb = Qb + (size_t)n * HD;          // [n][256]
    float* out = (float*)d_out;

    dim3 gg(n / GROWS, 2);
    qk_gemm_kernel<<<gg, 256, 0, stream>>>(X, Wq, bq, Wk, bk, Qb, Kb, n);

    attn_topk_kernel<<<n, 256, 0, stream>>>(Qb, Kb, nnpg, n_graphs, nrel, out, n);
}

// Round 17
// 142.371 us; speedup vs baseline: 1.0827x; 1.0057x over previous
//
#include <hip/hip_runtime.h>

#define NF    256   // IN_F
#define HD    256   // H*D
#define NH    4
#define DH    64
#define WINS  128   // WIN
#define HALFW 64
#define TOPK  32
#define GROWS 32    // rows per gemm block (4 waves x 8 rows)

typedef float vfloat4 __attribute__((ext_vector_type(4)));  // nt-store capable

// ------------- fused Q/K projection: X[n,256] @ W[256,256] + b -------------
// R15's exact kernel: W register double-buffer pipeline + s_load X +
// XCD-aware row swizzle (rows of segment-group x%8 -> XCD x%8).
__global__ __launch_bounds__(256) void qk_gemm_kernel(
    const float* __restrict__ X,
    const float* __restrict__ Wq, const float* __restrict__ bq,
    const float* __restrict__ Wk, const float* __restrict__ bk,
    float* __restrict__ Qb, float* __restrict__ Kb, int n)
{
    const int t    = threadIdx.x;
    const int wave = t >> 6;
    const int lane = t & 63;
    const bool isK = (blockIdx.y != 0);
    const float* W   = isK ? Wk : Wq;
    const float* bia = isK ? bk : bq;
    float*       Out = isK ? Kb : Qb;

    const int gx = gridDim.x;
    int bswz = blockIdx.x;
    if ((gx & 7) == 0) {
        int chunk = gx >> 3;
        bswz = (blockIdx.x & 7) * chunk + (blockIdx.x >> 3);
    }
    const int r0  = bswz * GROWS + wave * 8;
    const int r0s = __builtin_amdgcn_readfirstlane(r0);
    const float* Xs = X + (size_t)r0s * NF;        // scalar base -> s_load

    float4 acc[8];
#pragma unroll
    for (int r = 0; r < 8; ++r) acc[r] = make_float4(0.f, 0.f, 0.f, 0.f);

    float4 wA[8], wB[8];
    const float* Wl = W + 4 * lane;

#pragma unroll
    for (int u = 0; u < 8; ++u)                     // prologue: group 0
        wA[u] = *(const float4*)(Wl + (size_t)u * HD);

    for (int k = 0; k < NF; k += 16) {
        if (k + 8 < NF) {                           // prefetch group g+1
#pragma unroll
            for (int u = 0; u < 8; ++u)
                wB[u] = *(const float4*)(Wl + (size_t)(k + 8 + u) * HD);
        }
#pragma unroll
        for (int u = 0; u < 8; ++u) {
#pragma unroll
            for (int r = 0; r < 8; ++r) {
                float xk = Xs[r * NF + k + u];      // SGPR broadcast
                acc[r].x += xk * wA[u].x;
                acc[r].y += xk * wA[u].y;
                acc[r].z += xk * wA[u].z;
                acc[r].w += xk * wA[u].w;
            }
        }
        if (k + 16 < NF) {                          // prefetch group g+2
#pragma unroll
            for (int u = 0; u < 8; ++u)
                wA[u] = *(const float4*)(Wl + (size_t)(k + 16 + u) * HD);
        }
#pragma unroll
        for (int u = 0; u < 8; ++u) {
#pragma unroll
            for (int r = 0; r < 8; ++r) {
                float xk = Xs[r * NF + k + 8 + u];  // SGPR broadcast
                acc[r].x += xk * wB[u].x;
                acc[r].y += xk * wB[u].y;
                acc[r].z += xk * wB[u].z;
                acc[r].w += xk * wB[u].w;
            }
        }
    }

    const float4 bv = *(const float4*)(bia + 4 * lane);
#pragma unroll
    for (int r = 0; r < 8; ++r) {
        acc[r].x += bv.x; acc[r].y += bv.y; acc[r].z += bv.z; acc[r].w += bv.w;
        *(float4*)(Out + (size_t)(r0 + r) * HD + 4 * lane) = acc[r];  // coalesced
    }
}

// ---- per-node windowed attention + top-32 + overlapped nt row write ----
// (a) nontemporal stores: 64MiB output stream doesn't evict XCD-local K rows
// from L2; (b) zero portion issued right AFTER the score-phase K loads (no
// later vmem loads stall behind stores) so the drain overlaps softmax/rank.
__global__ __launch_bounds__(256) void attn_topk_kernel(
    const float* __restrict__ Q,
    const float* __restrict__ K,
    const int* __restrict__ nnpg, int n_graphs,
    const int* __restrict__ nrel,
    float* __restrict__ out, int n)
{
    const int t    = threadIdx.x;
    const int wave = t >> 6;
    const int lane = t & 63;

    int i = blockIdx.x;
    const int nb = gridDim.x;
    if ((nb & 7) == 0) {                      // bijective XCD swizzle
        int chunk = nb >> 3;
        i = (blockIdx.x & 7) * chunk + (blockIdx.x >> 3);
    }

    __shared__ float sc[NH][WINS + 8];  // +8 pad: conflict-free head writes
    __shared__ float pr[NH][WINS];
    __shared__ float attnv[WINS];
    __shared__ float slotval[WINS];

    // segment bounds: tile(nnpg, R) -> cumsum -> searchsorted(right)
    int R = nrel[0];
    int total = n_graphs * R;
    int seg_start = 0, seg_end = n;
    int cum = 0;
    for (int e = 0; e < total; ++e) {
        int sz = nnpg[e % n_graphs];
        int nc = cum + sz;
        if (i < nc) { seg_start = cum; seg_end = nc; break; }
        cum = nc;
    }
    const int start = max(seg_start, i - HALFW);
    const int end   = min(seg_end,   i + HALFW);
    const int win   = end - start;            // >= 64 (segments >= 128 nodes)

    const float4 q4 = *(const float4*)(Q + (size_t)i * HD + lane * 4);

    // ---- scores: wave w handles rows {w + 4j}; 8-deep independent loads ----
#pragma unroll 8
    for (int j = 0; j < 32; ++j) {
        int row = wave + 4 * j;               // 0..127
        float v = 0.f;
        if (row < win) {
            float4 k4 = *(const float4*)(K + (size_t)(start + row) * HD + lane * 4);
            v = q4.x * k4.x + q4.y * k4.y + q4.z * k4.z + q4.w * k4.w;
        }
        v += __shfl_xor(v, 1);
        v += __shfl_xor(v, 2);
        v += __shfl_xor(v, 4);
        v += __shfl_xor(v, 8);
        if ((lane & 15) == 0)
            sc[lane >> 4][row] = v * 0.25f;   // /sqrt(64)/tau; padded rows -> 0
    }

    // ---- overlapped zero-write: all float4s outside the window region ----
    vfloat4* orow = (vfloat4*)(out + (size_t)i * n);
    const int n4  = n >> 2;
    const int lo4 = start >> 2;
    const int hi4 = (end - 1) >> 2;           // inclusive
    const vfloat4 z4 = {0.f, 0.f, 0.f, 0.f};
    for (int c4 = t; c4 < n4; c4 += 256) {
        if (c4 >= lo4 && c4 <= hi4) continue;
        __builtin_nontemporal_store(z4, &orow[c4]);
    }
    __syncthreads();

    // ---- per-head softmax over full 128-slot window: wave w = head w ----
    {
        float v0 = sc[wave][lane], v1 = sc[wave][lane + 64];
        float mx = fmaxf(v0, v1);
#pragma unroll
        for (int off = 32; off > 0; off >>= 1) mx = fmaxf(mx, __shfl_xor(mx, off));
        float e0 = expf(v0 - mx), e1 = expf(v1 - mx);
        float sm = e0 + e1;
#pragma unroll
        for (int off = 32; off > 0; off >>= 1) sm += __shfl_xor(sm, off);
        pr[wave][lane]      = e0 / sm;
        pr[wave][lane + 64] = e1 / sm;
    }
    __syncthreads();

    // ---- mean over heads; invalid slots excluded from top-k ----
    if (t < WINS) {
        float a = 0.25f * (pr[0][t] + pr[1][t] + pr[2][t] + pr[3][t]);
        attnv[t] = (t < win) ? a : -1.0f;
    }
    __syncthreads();

    // ---- stable top-32 rank count (lower index wins ties, like lax.top_k) ----
    if (t < WINS) {
        float v = attnv[t];
        int cnt = 0;
#pragma unroll
        for (int j4 = 0; j4 < WINS / 4; ++j4) {
            float4 a4 = *(const float4*)&attnv[j4 * 4];
            int jb = j4 * 4;
            cnt += (a4.x > v) || (a4.x == v && (jb + 0) < t);
            cnt += (a4.y > v) || (a4.y == v && (jb + 1) < t);
            cnt += (a4.z > v) || (a4.z == v && (jb + 2) < t);
            cnt += (a4.w > v) || (a4.w == v && (jb + 3) < t);
        }
        slotval[t] = (t < win && cnt < TOPK) ? 1.0f : 0.0f;
    }
    __syncthreads();

    // ---- final pass: the <=34 window float4s (zeros merged at edges) ----
    {
        int c4 = lo4 + t;
        if (c4 <= hi4) {
            int c = c4 << 2;
            int o0 = c - start, o1 = o0 + 1, o2 = o0 + 2, o3 = o0 + 3;
            vfloat4 v4;
            v4.x = (o0 >= 0 && o0 < WINS) ? slotval[o0] : 0.f;
            v4.y = (o1 >= 0 && o1 < WINS) ? slotval[o1] : 0.f;
            v4.z = (o2 >= 0 && o2 < WINS) ? slotval[o2] : 0.f;
            v4.w = (o3 >= 0 && o3 < WINS) ? slotval[o3] : 0.f;
            __builtin_nontemporal_store(v4, &orow[c4]);
        }
    }
}

extern "C" void kernel_launch(void* const* d_in, const int* in_sizes, int n_in,
                              void* d_out, int out_size, void* d_ws, size_t ws_size,
                              hipStream_t stream)
{
    const float* X  = (const float*)d_in[0];
    const float* Wq = (const float*)d_in[1];
    const float* bq = (const float*)d_in[2];
    const float* Wk = (const float*)d_in[3];
    const float* bk = (const float*)d_in[4];
    const int* nnpg = (const int*)d_in[5];
    const int* nrel = (const int*)d_in[6];

    const int n = in_sizes[0] / NF;
    const int n_graphs = in_sizes[5];

    float* Qb = (float*)d_ws;                 // [n][256]
    float* Kb = Qb + (size_t)n * HD;          // [n][256]
    float* out = (float*)d_out;

    dim3 gg(n / GROWS, 2);
    qk_gemm_kernel<<<gg, 256, 0, stream>>>(X, Wq, bq, Wk, bk, Qb, Kb, n);

    attn_topk_kernel<<<n, 256, 0, stream>>>(Qb, Kb, nnpg, n_graphs, nrel, out, n);
}

// Round 18
// 135.970 us; speedup vs baseline: 1.1337x; 1.0471x over previous
//
#include <hip/hip_runtime.h>

#define NF    256   // IN_F
#define HD    256   // H*D
#define NH    4
#define DH    64
#define WINS  128   // WIN
#define HALFW 64
#define TOPK  32
#define GROWS 32    // rows per gemm block (4 waves x 8 rows)

typedef float vfloat4 __attribute__((ext_vector_type(4)));  // nt-store capable

// 16-lane sum via DPP (all-VALU, zero DS ops). After the 4 adds every lane
// in each 16-lane group holds the group sum.
__device__ __forceinline__ float dpp_add16(float v) {
    int x;
    x = __builtin_amdgcn_update_dpp(0, __float_as_int(v), 0xB1, 0xF, 0xF, true);  // quad_perm xor1
    v += __int_as_float(x);
    x = __builtin_amdgcn_update_dpp(0, __float_as_int(v), 0x4E, 0xF, 0xF, true);  // quad_perm xor2
    v += __int_as_float(x);
    x = __builtin_amdgcn_update_dpp(0, __float_as_int(v), 0x124, 0xF, 0xF, true); // row_ror:4
    v += __int_as_float(x);
    x = __builtin_amdgcn_update_dpp(0, __float_as_int(v), 0x128, 0xF, 0xF, true); // row_ror:8
    v += __int_as_float(x);
    return v;
}

// ------------- fused Q/K projection: X[n,256] @ W[256,256] + b -------------
// R15's exact kernel: W register double-buffer pipeline + s_load X +
// XCD-aware row swizzle (rows of segment-group x%8 -> XCD x%8).
__global__ __launch_bounds__(256) void qk_gemm_kernel(
    const float* __restrict__ X,
    const float* __restrict__ Wq, const float* __restrict__ bq,
    const float* __restrict__ Wk, const float* __restrict__ bk,
    float* __restrict__ Qb, float* __restrict__ Kb, int n)
{
    const int t    = threadIdx.x;
    const int wave = t >> 6;
    const int lane = t & 63;
    const bool isK = (blockIdx.y != 0);
    const float* W   = isK ? Wk : Wq;
    const float* bia = isK ? bk : bq;
    float*       Out = isK ? Kb : Qb;

    const int gx = gridDim.x;
    int bswz = blockIdx.x;
    if ((gx & 7) == 0) {
        int chunk = gx >> 3;
        bswz = (blockIdx.x & 7) * chunk + (blockIdx.x >> 3);
    }
    const int r0  = bswz * GROWS + wave * 8;
    const int r0s = __builtin_amdgcn_readfirstlane(r0);
    const float* Xs = X + (size_t)r0s * NF;        // scalar base -> s_load

    float4 acc[8];
#pragma unroll
    for (int r = 0; r < 8; ++r) acc[r] = make_float4(0.f, 0.f, 0.f, 0.f);

    float4 wA[8], wB[8];
    const float* Wl = W + 4 * lane;

#pragma unroll
    for (int u = 0; u < 8; ++u)                     // prologue: group 0
        wA[u] = *(const float4*)(Wl + (size_t)u * HD);

    for (int k = 0; k < NF; k += 16) {
        if (k + 8 < NF) {                           // prefetch group g+1
#pragma unroll
            for (int u = 0; u < 8; ++u)
                wB[u] = *(const float4*)(Wl + (size_t)(k + 8 + u) * HD);
        }
#pragma unroll
        for (int u = 0; u < 8; ++u) {
#pragma unroll
            for (int r = 0; r < 8; ++r) {
                float xk = Xs[r * NF + k + u];      // SGPR broadcast
                acc[r].x += xk * wA[u].x;
                acc[r].y += xk * wA[u].y;
                acc[r].z += xk * wA[u].z;
                acc[r].w += xk * wA[u].w;
            }
        }
        if (k + 16 < NF) {                          // prefetch group g+2
#pragma unroll
            for (int u = 0; u < 8; ++u)
                wA[u] = *(const float4*)(Wl + (size_t)(k + 16 + u) * HD);
        }
#pragma unroll
        for (int u = 0; u < 8; ++u) {
#pragma unroll
            for (int r = 0; r < 8; ++r) {
                float xk = Xs[r * NF + k + 8 + u];  // SGPR broadcast
                acc[r].x += xk * wB[u].x;
                acc[r].y += xk * wB[u].y;
                acc[r].z += xk * wB[u].z;
                acc[r].w += xk * wB[u].w;
            }
        }
    }

    const float4 bv = *(const float4*)(bia + 4 * lane);
#pragma unroll
    for (int r = 0; r < 8; ++r) {
        acc[r].x += bv.x; acc[r].y += bv.y; acc[r].z += bv.z; acc[r].w += bv.w;
        *(float4*)(Out + (size_t)(r0 + r) * HD + 4 * lane) = acc[r];  // coalesced
    }
}

// ---- per-node windowed attention + top-32 + overlapped nt row write ----
// R17 + score-phase reduction via DPP adds (0 DS ops) instead of 4 shfl_xor.
__global__ __launch_bounds__(256) void attn_topk_kernel(
    const float* __restrict__ Q,
    const float* __restrict__ K,
    const int* __restrict__ nnpg, int n_graphs,
    const int* __restrict__ nrel,
    float* __restrict__ out, int n)
{
    const int t    = threadIdx.x;
    const int wave = t >> 6;
    const int lane = t & 63;

    int i = blockIdx.x;
    const int nb = gridDim.x;
    if ((nb & 7) == 0) {                      // bijective XCD swizzle
        int chunk = nb >> 3;
        i = (blockIdx.x & 7) * chunk + (blockIdx.x >> 3);
    }

    __shared__ float sc[NH][WINS + 8];  // +8 pad: conflict-free head writes
    __shared__ float pr[NH][WINS];
    __shared__ float attnv[WINS];
    __shared__ float slotval[WINS];

    // segment bounds: tile(nnpg, R) -> cumsum -> searchsorted(right)
    int R = nrel[0];
    int total = n_graphs * R;
    int seg_start = 0, seg_end = n;
    int cum = 0;
    for (int e = 0; e < total; ++e) {
        int sz = nnpg[e % n_graphs];
        int nc = cum + sz;
        if (i < nc) { seg_start = cum; seg_end = nc; break; }
        cum = nc;
    }
    const int start = max(seg_start, i - HALFW);
    const int end   = min(seg_end,   i + HALFW);
    const int win   = end - start;            // >= 64 (segments >= 128 nodes)

    const float4 q4 = *(const float4*)(Q + (size_t)i * HD + lane * 4);

    // ---- scores: wave w handles rows {w + 4j}; DPP 16-lane reduction ----
#pragma unroll 8
    for (int j = 0; j < 32; ++j) {
        int row = wave + 4 * j;               // 0..127
        float v = 0.f;
        if (row < win) {
            float4 k4 = *(const float4*)(K + (size_t)(start + row) * HD + lane * 4);
            v = q4.x * k4.x + q4.y * k4.y + q4.z * k4.z + q4.w * k4.w;
        }
        v = dpp_add16(v);                     // all-VALU 16-lane sum
        if ((lane & 15) == 0)
            sc[lane >> 4][row] = v * 0.25f;   // /sqrt(64)/tau; padded rows -> 0
    }

    // ---- overlapped zero-write: all float4s outside the window region ----
    vfloat4* orow = (vfloat4*)(out + (size_t)i * n);
    const int n4  = n >> 2;
    const int lo4 = start >> 2;
    const int hi4 = (end - 1) >> 2;           // inclusive
    const vfloat4 z4 = {0.f, 0.f, 0.f, 0.f};
    for (int c4 = t; c4 < n4; c4 += 256) {
        if (c4 >= lo4 && c4 <= hi4) continue;
        __builtin_nontemporal_store(z4, &orow[c4]);
    }
    __syncthreads();

    // ---- per-head softmax over full 128-slot window: wave w = head w ----
    {
        float v0 = sc[wave][lane], v1 = sc[wave][lane + 64];
        float mx = fmaxf(v0, v1);
#pragma unroll
        for (int off = 32; off > 0; off >>= 1) mx = fmaxf(mx, __shfl_xor(mx, off));
        float e0 = expf(v0 - mx), e1 = expf(v1 - mx);
        float sm = e0 + e1;
#pragma unroll
        for (int off = 32; off > 0; off >>= 1) sm += __shfl_xor(sm, off);
        pr[wave][lane]      = e0 / sm;
        pr[wave][lane + 64] = e1 / sm;
    }
    __syncthreads();

    // ---- mean over heads; invalid slots excluded from top-k ----
    if (t < WINS) {
        float a = 0.25f * (pr[0][t] + pr[1][t] + pr[2][t] + pr[3][t]);
        attnv[t] = (t < win) ? a : -1.0f;
    }
    __syncthreads();

    // ---- stable top-32 rank count (lower index wins ties, like lax.top_k) ----
    if (t < WINS) {
        float v = attnv[t];
        int cnt = 0;
#pragma unroll
        for (int j4 = 0; j4 < WINS / 4; ++j4) {
            float4 a4 = *(const float4*)&attnv[j4 * 4];
            int jb = j4 * 4;
            cnt += (a4.x > v) || (a4.x == v && (jb + 0) < t);
            cnt += (a4.y > v) || (a4.y == v && (jb + 1) < t);
            cnt += (a4.z > v) || (a4.z == v && (jb + 2) < t);
            cnt += (a4.w > v) || (a4.w == v && (jb + 3) < t);
        }
        slotval[t] = (t < win && cnt < TOPK) ? 1.0f : 0.0f;
    }
    __syncthreads();

    // ---- final pass: the <=34 window float4s (zeros merged at edges) ----
    {
        int c4 = lo4 + t;
        if (c4 <= hi4) {
            int c = c4 << 2;
            int o0 = c - start, o1 = o0 + 1, o2 = o0 + 2, o3 = o0 + 3;
            vfloat4 v4;
            v4.x = (o0 >= 0 && o0 < WINS) ? slotval[o0] : 0.f;
            v4.y = (o1 >= 0 && o1 < WINS) ? slotval[o1] : 0.f;
            v4.z = (o2 >= 0 && o2 < WINS) ? slotval[o2] : 0.f;
            v4.w = (o3 >= 0 && o3 < WINS) ? slotval[o3] : 0.f;
            __builtin_nontemporal_store(v4, &orow[c4]);
        }
    }
}

extern "C" void kernel_launch(void* const* d_in, const int* in_sizes, int n_in,
                              void* d_out, int out_size, void* d_ws, size_t ws_size,
                              hipStream_t stream)
{
    const float* X  = (const float*)d_in[0];
    const float* Wq = (const float*)d_in[1];
    const float* bq = (const float*)d_in[2];
    const float* Wk = (const float*)d_in[3];
    const float* bk = (const float*)d_in[4];
    const int* nnpg = (const int*)d_in[5];
    const int* nrel = (const int*)d_in[6];

    const int n = in_sizes[0] / NF;
    const int n_graphs = in_sizes[5];

    float* Qb = (float*)d_ws;                 // [n][256]
    float* Kb = Qb + (size_t)n * HD;          // [n][256]
    float* out = (float*)d_out;

    dim3 gg(n / GROWS, 2);
    qk_gemm_kernel<<<gg, 256, 0, stream>>>(X, Wq, bq, Wk, bk, Qb, Kb, n);

    attn_topk_kernel<<<n, 256, 0, stream>>>(Qb, Kb, nnpg, n_graphs, nrel, out, n);
}